// Round 4
// baseline (1611.404 us; speedup 1.0000x reference)
//
#include <hip/hip_runtime.h>

typedef float4 f4;

// ---- ws float-offset layout ----
#define F_S0   0        // 64: per-row W0 scales
#define F_BN0  64       // g[64] be[64] m[64] r[64]
#define F_BN1  320
#define F_BN2  576
#define F_BN3  832      // g[16] be[16] m[16] r[16]
#define F_WQ1  896      // 4096 fp32
#define F_WQ2  4992     // 4096 fp32
#define F_WQ3  9088     // 640 fp32
#define F_WI8  9728     // int8 tiled W0: 196608 B = 49152 floats
#define F_WQ0  58880    // fp32 tiled W0: 196608 floats (optional)
#define WS_NEED_F32 ((size_t)(F_WQ0 + 196608) * 4)

struct InPtrs { const float* p[25]; };

// ---------------- prep ----------------
__global__ __launch_bounds__(256) void qtfc_prep(InPtrs P, float* __restrict__ wsf, int wf32) {
#pragma clang fp contract(off)
  __shared__ float red[256];
  const int tid = threadIdx.x, b = blockIdx.x;
  if (b < 64) {
    const int row = b;
    const float* W = P.p[1];
    float mx = 0.f;
    for (int k = tid; k < 3072; k += 256) mx = fmaxf(mx, fabsf(W[row * 3072 + k]));
    red[tid] = mx; __syncthreads();
    for (int s = 128; s > 0; s >>= 1) { if (tid < s) red[tid] = fmaxf(red[tid], red[tid + s]); __syncthreads(); }
    const float sv = fmaxf(__fdiv_rn(red[0], 7.f), 1e-8f);
    const int g = row >> 3, jj = row & 7;
    signed char* wi8 = (signed char*)(wsf + F_WI8);
    float* wq0 = wsf + F_WQ0;
    for (int k = tid; k < 3072; k += 256) {
      const float r = rintf(__fdiv_rn(W[row * 3072 + k], sv));
      const int idx = (((g * 96 + (k >> 5)) * 8 + ((k >> 2) & 7)) * 32) + jj * 4 + (k & 3);
      wi8[idx] = (signed char)(int)r;
      if (wf32) wq0[idx] = __fmul_rn(r, sv);
    }
    if (tid == 0) {
      wsf[F_S0 + row] = sv;
      const float gg = P.p[3][row], be = P.p[4][row], m = P.p[5][row], v = P.p[6][row];
      const float rr = __fdiv_rn(1.f, __fsqrt_rn(__fadd_rn(v, 1e-5f)));
      wsf[F_BN0 + row] = gg; wsf[F_BN0 + 64 + row] = be; wsf[F_BN0 + 128 + row] = m; wsf[F_BN0 + 192 + row] = rr;
    }
  } else if (b < 192) {
    const int lay = b >> 6, row = b & 63;   // lay = 1,2
    const float* W = P.p[1 + 6 * lay];
    red[tid] = (tid < 64) ? fabsf(W[row * 64 + tid]) : 0.f; __syncthreads();
    for (int s = 128; s > 0; s >>= 1) { if (tid < s) red[tid] = fmaxf(red[tid], red[tid + s]); __syncthreads(); }
    const float sv = fmaxf(__fdiv_rn(red[0], 7.f), 1e-8f);
    float* wq = wsf + (lay == 1 ? F_WQ1 : F_WQ2);
    if (tid < 64)
      wq[row * 64 + tid] = __fmul_rn(rintf(__fdiv_rn(W[row * 64 + tid], sv)), sv);
    if (tid == 0) {
      const int base = (lay == 1) ? F_BN1 : F_BN2;
      const float gg = P.p[3 + 6 * lay][row], be = P.p[4 + 6 * lay][row];
      const float m = P.p[5 + 6 * lay][row], v = P.p[6 + 6 * lay][row];
      const float rr = __fdiv_rn(1.f, __fsqrt_rn(__fadd_rn(v, 1e-5f)));
      wsf[base + row] = gg; wsf[base + 64 + row] = be; wsf[base + 128 + row] = m; wsf[base + 192 + row] = rr;
    }
  } else {
    const float* W = P.p[19];
    float mx = 0.f;
    for (int k = tid; k < 640; k += 256) mx = fmaxf(mx, fabsf(W[k]));
    red[tid] = mx; __syncthreads();
    for (int s = 128; s > 0; s >>= 1) { if (tid < s) red[tid] = fmaxf(red[tid], red[tid + s]); __syncthreads(); }
    const float sv = fmaxf(__fdiv_rn(red[0], 7.f), 1e-8f);
    for (int k = tid; k < 640; k += 256)
      wsf[F_WQ3 + k] = __fmul_rn(rintf(__fdiv_rn(W[k], sv)), sv);
    if (tid < 10) {
      const float gg = P.p[21][tid], be = P.p[22][tid], m = P.p[23][tid], v = P.p[24][tid];
      const float rr = __fdiv_rn(1.f, __fsqrt_rn(__fadd_rn(v, 1e-5f)));
      wsf[F_BN3 + tid] = gg; wsf[F_BN3 + 16 + tid] = be; wsf[F_BN3 + 32 + tid] = m; wsf[F_BN3 + 48 + tid] = rr;
    }
  }
}

// ---------------- exact-np helpers ----------------
__device__ __forceinline__ float bn_act4(float hv, float g, float be, float m, float r) {
#pragma clang fp contract(off)
  const float bnv = __fadd_rn(__fmul_rn(__fmul_rn(g, __fsub_rn(hv, m)), r), be);
  const float y = fminf(fmaxf(bnv, -1.f), 1.f);
  return __fdiv_rn(rintf(__fmul_rn(y, 7.f)), 7.f);
}
__device__ __forceinline__ float lutq(float v, const float* lut) {
#pragma clang fp contract(off)
  const float y = fminf(fmaxf(v, -1.f), 1.f);
  const float r = rintf(__fmul_rn(y, 127.f));
  return lut[(int)r + 127];
}

__device__ __forceinline__ void fmas(const f4 (&xa)[4], const f4 (&wb)[8], float (&acc)[4][8]) {
#pragma clang fp contract(off)
#pragma unroll
  for (int i = 0; i < 4; ++i)
#pragma unroll
    for (int j = 0; j < 8; ++j) {
      acc[i][j] = __fmaf_rn(xa[i].x, wb[j].x, acc[i][j]);
      acc[i][j] = __fmaf_rn(xa[i].y, wb[j].y, acc[i][j]);
      acc[i][j] = __fmaf_rn(xa[i].z, wb[j].z, acc[i][j]);
      acc[i][j] = __fmaf_rn(xa[i].w, wb[j].w, acc[i][j]);
    }
}
__device__ __forceinline__ void fmas8(const f4 (&xa)[4], const int (&wd)[8],
                                      const float (&svj)[8], float (&acc)[4][8]) {
#pragma clang fp contract(off)
#pragma unroll
  for (int j = 0; j < 8; ++j) {
    const int d = wd[j];
    float wf[4];
#pragma unroll
    for (int e = 0; e < 4; ++e)
      wf[e] = __fmul_rn((float)((signed char)((d >> (8 * e)) & 255)), svj[j]);
#pragma unroll
    for (int i = 0; i < 4; ++i) {
      acc[i][j] = __fmaf_rn(xa[i].x, wf[0], acc[i][j]);
      acc[i][j] = __fmaf_rn(xa[i].y, wf[1], acc[i][j]);
      acc[i][j] = __fmaf_rn(xa[i].z, wf[2], acc[i][j]);
      acc[i][j] = __fmaf_rn(xa[i].w, wf[3], acc[i][j]);
    }
  }
}

__device__ __forceinline__ void load_xa(const float* xt, int rq, int s, f4 (&xa)[4]) {
#pragma unroll
  for (int i = 0; i < 4; ++i)
    xa[i] = *(const f4*)(xt + ((rq * 4 + i) * 8 + (s ^ rq)) * 4);
}

__device__ __forceinline__ void layer64(const float* src, float* dst,
                                        const float* __restrict__ wq,
                                        const float* __restrict__ bn, int rq, int cq) {
#pragma clang fp contract(off)
#pragma unroll
  for (int i = 0; i < 4; ++i) {
    const int row = rq * 4 + i;
    f4 av[16];
#pragma unroll
    for (int s = 0; s < 16; ++s) {
      const int sw = (s & 8) | ((s & 7) ^ rq);
      av[s] = *(const f4*)(src + row * 64 + sw * 4);
    }
#pragma unroll
    for (int j = 0; j < 8; ++j) {
      const int ch = cq * 8 + j;
      float a = 0.f;
#pragma unroll
      for (int s = 0; s < 16; ++s) {
        const f4 wv = *(const f4*)(wq + ch * 64 + s * 4);
        a = __fmaf_rn(av[s].x, wv.x, a);
        a = __fmaf_rn(av[s].y, wv.y, a);
        a = __fmaf_rn(av[s].z, wv.z, a);
        a = __fmaf_rn(av[s].w, wv.w, a);
      }
      const float af = bn_act4(a, bn[ch], bn[64 + ch], bn[128 + ch], bn[192 + ch]);
      const int slot = ch >> 2;
      const int sw = (slot & 8) | ((slot & 7) ^ rq);
      dst[row * 64 + sw * 4 + (ch & 3)] = af;
    }
  }
}

// ---------------- main: 1 wave per block, 32 rows, no barriers ----------------
template<int W8>
__global__ __launch_bounds__(64) void qtfc_main(const float* __restrict__ x,
                                                const float* __restrict__ wsf,
                                                float* __restrict__ out) {
#pragma clang fp contract(off)
  __shared__ float smem[4352];  // [0:1024) xt | [4096:4352) lut ; later a1=[0:2048) a2=[2048:4096)
  const int l = threadIdx.x;
  const int rq = l >> 3, cq = l & 7;
  const int row0 = blockIdx.x * 32;
  float* xt = smem;
  float* lut = smem + 4096;

#pragma unroll
  for (int ii = 0; ii < 4; ++ii) {
    const int idx = l * 4 + ii;
    lut[idx] = __fdiv_rn((float)(idx - 127), 127.f);
  }

  float svj[8];
  if (W8) {
#pragma unroll
    for (int j = 0; j < 8; ++j) svj[j] = wsf[F_S0 + cq * 8 + j];
  }

  // x staging: lane stages 4 f4; instr i covers rows 8i..8i+7
  const float* xb[4];
  f4 gx[4];
  int stw[4];
#pragma unroll
  for (int i = 0; i < 4; ++i) {
    const int r = 8 * i + (l >> 3);
    xb[i] = x + (long)(row0 + r) * 3072 + (l & 7) * 4;
    gx[i] = *(const f4*)(xb[i]);
    stw[i] = r * 8 + ((l & 7) ^ ((r >> 2) & 7));
  }

  float acc[4][8], h[4][8];
#pragma unroll
  for (int i = 0; i < 4; ++i)
#pragma unroll
    for (int j = 0; j < 8; ++j) { acc[i][j] = 0.f; h[i][j] = 0.f; }

  const f4* wbase_f = (const f4*)(wsf + F_WQ0) + (long)cq * 96 * 64;
  const int4* wbase_8 = (const int4*)(wsf + F_WI8) + (long)cq * 96 * 16;

#pragma unroll 1
  for (int t = 0; t < 96; ++t) {
    // stage tile t (quant via LUT), wave-private LDS, in-order
#pragma unroll
    for (int i = 0; i < 4; ++i) {
      f4 q;
      q.x = lutq(gx[i].x, lut); q.y = lutq(gx[i].y, lut);
      q.z = lutq(gx[i].z, lut); q.w = lutq(gx[i].w, lut);
      ((f4*)xt)[stw[i]] = q;
    }
    // prefetch x tile t+1
    const int tn = (t < 95) ? t + 1 : 95;
#pragma unroll
    for (int i = 0; i < 4; ++i) gx[i] = *(const f4*)(xb[i] + tn * 32);

    if (!W8) {
      const f4* wb_t = wbase_f + t * 64;
      f4 xaA[4], wbA[8], xaB[4], wbB[8];
      load_xa(xt, rq, 0, xaA);
#pragma unroll
      for (int j = 0; j < 8; ++j) wbA[j] = wb_t[j];
#pragma unroll
      for (int s = 0; s < 8; ++s) {
        if ((s & 1) == 0) {
          if (s < 7) {
            load_xa(xt, rq, s + 1, xaB);
#pragma unroll
            for (int j = 0; j < 8; ++j) wbB[j] = wb_t[(s + 1) * 8 + j];
          }
          fmas(xaA, wbA, acc);
        } else {
          if (s < 7) {
            load_xa(xt, rq, s + 1, xaA);
#pragma unroll
            for (int j = 0; j < 8; ++j) wbA[j] = wb_t[(s + 1) * 8 + j];
          }
          fmas(xaB, wbB, acc);
        }
        __builtin_amdgcn_sched_barrier(0);
      }
    } else {
      const int4* w8_t = wbase_8 + t * 16;
      f4 xaA[4], xaB[4];
      int wdA[8], wdB[8];
      load_xa(xt, rq, 0, xaA);
      { int4 a = w8_t[0], b = w8_t[1];
        wdA[0]=a.x; wdA[1]=a.y; wdA[2]=a.z; wdA[3]=a.w; wdA[4]=b.x; wdA[5]=b.y; wdA[6]=b.z; wdA[7]=b.w; }
#pragma unroll
      for (int s = 0; s < 8; ++s) {
        if ((s & 1) == 0) {
          if (s < 7) {
            load_xa(xt, rq, s + 1, xaB);
            int4 a = w8_t[(s + 1) * 2], b = w8_t[(s + 1) * 2 + 1];
            wdB[0]=a.x; wdB[1]=a.y; wdB[2]=a.z; wdB[3]=a.w; wdB[4]=b.x; wdB[5]=b.y; wdB[6]=b.z; wdB[7]=b.w;
          }
          fmas8(xaA, wdA, svj, acc);
        } else {
          if (s < 7) {
            load_xa(xt, rq, s + 1, xaA);
            int4 a = w8_t[(s + 1) * 2], b = w8_t[(s + 1) * 2 + 1];
            wdA[0]=a.x; wdA[1]=a.y; wdA[2]=a.z; wdA[3]=a.w; wdA[4]=b.x; wdA[5]=b.y; wdA[6]=b.z; wdA[7]=b.w;
          }
          fmas8(xaB, wdB, svj, acc);
        }
        __builtin_amdgcn_sched_barrier(0);
      }
    }

    if ((t % 12) == 11) {   // end of KC=384 block: sequential fp32 block-sum combine
#pragma unroll
      for (int i = 0; i < 4; ++i)
#pragma unroll
        for (int j = 0; j < 8; ++j) { h[i][j] = __fadd_rn(h[i][j], acc[i][j]); acc[i][j] = 0.f; }
    }
  }

  // ---- layer-0 epilogue: BN + 4-bit act -> a1 ----
  float* a1 = smem;
  float* a2 = smem + 2048;
  {
    const float* bn0 = wsf + F_BN0;
#pragma unroll
    for (int i = 0; i < 4; ++i) {
      const int row = rq * 4 + i;
#pragma unroll
      for (int j = 0; j < 8; ++j) {
        const int ch = cq * 8 + j;
        const float af = bn_act4(h[i][j], bn0[ch], bn0[64 + ch], bn0[128 + ch], bn0[192 + ch]);
        const int slot = ch >> 2;
        const int sw = (slot & 8) | ((slot & 7) ^ rq);
        a1[row * 64 + sw * 4 + (ch & 3)] = af;
      }
    }
  }

  layer64(a1, a2, wsf + F_WQ1, wsf + F_BN1, rq, cq);
  layer64(a2, a1, wsf + F_WQ2, wsf + F_BN2, rq, cq);

  // ---- layer 3: 10 outputs, BN, no act ----
  {
    const float* wq3 = wsf + F_WQ3;
    const float* bn3 = wsf + F_BN3;
#pragma unroll
    for (int i = 0; i < 4; ++i) {
      const int row = rq * 4 + i;
      f4 av[16];
#pragma unroll
      for (int s = 0; s < 16; ++s) {
        const int sw = (s & 8) | ((s & 7) ^ rq);
        av[s] = *(const f4*)(a1 + row * 64 + sw * 4);
      }
#pragma unroll
      for (int j = 0; j < 8; ++j) {
        const int ch = cq * 8 + j;
        if (ch < 10) {
          float a = 0.f;
#pragma unroll
          for (int s = 0; s < 16; ++s) {
            const f4 wv = *(const f4*)(wq3 + ch * 64 + s * 4);
            a = __fmaf_rn(av[s].x, wv.x, a);
            a = __fmaf_rn(av[s].y, wv.y, a);
            a = __fmaf_rn(av[s].z, wv.z, a);
            a = __fmaf_rn(av[s].w, wv.w, a);
          }
          const float o = __fadd_rn(__fmul_rn(__fmul_rn(bn3[ch], __fsub_rn(a, bn3[32 + ch])), bn3[48 + ch]), bn3[16 + ch]);
          out[(long)(row0 + row) * 10 + ch] = o;
        }
      }
    }
  }
}

extern "C" void kernel_launch(void* const* d_in, const int* in_sizes, int n_in,
                              void* d_out, int out_size, void* d_ws, size_t ws_size,
                              hipStream_t stream) {
  (void)in_sizes; (void)n_in; (void)out_size;
  InPtrs P;
  for (int i = 0; i < 25; ++i) P.p[i] = (const float*)d_in[i];
  float* wsf = (float*)d_ws;
  const int wf32 = (ws_size >= WS_NEED_F32) ? 1 : 0;
  qtfc_prep<<<193, 256, 0, stream>>>(P, wsf, wf32);
  if (wf32)
    qtfc_main<0><<<1024, 64, 0, stream>>>((const float*)d_in[0], wsf, (float*)d_out);
  else
    qtfc_main<1><<<1024, 64, 0, stream>>>((const float*)d_in[0], wsf, (float*)d_out);
}